// Round 14
// baseline (908.912 us; speedup 1.0000x reference)
//
#include <hip/hip_runtime.h>

#define H 2048
#define TT 4096
#define BB 4
#define NROWS (BB * TT)               // 16384
#define NTH ((size_t)NROWS * H)       // 33,554,432
#define KCAT (H + 32)                 // 2080 (decay path)
#define KC8  (H + 64)                 // 2112 (bigproj, zero-padded)
#define NTH64 ((size_t)NROWS * 64)

typedef __attribute__((ext_vector_type(8))) short bh8;
typedef __attribute__((ext_vector_type(4))) float f32x4;

__device__ inline unsigned short f2bf(float f) {
    union { float f; unsigned u; } v; v.f = f;
    unsigned r = v.u + 0x7fff + ((v.u >> 16) & 1);   // RNE
    return (unsigned short)(r >> 16);
}
__device__ inline float bf2f(unsigned short u) {
    union { unsigned u; float f; } v; v.u = ((unsigned)u) << 16; return v.f;
}
__device__ inline void gload_lds16(const void* g, void* l) {
    __builtin_amdgcn_global_load_lds(
        (const __attribute__((address_space(1))) void*)g,
        (__attribute__((address_space(3))) void*)l, 16, 0, 0);
}

// ---------------- prep: shifted & xin (bf16), vectorized ----------------
__global__ __launch_bounds__(256) void prep_kernel(
    const float* __restrict__ hidden, const float* __restrict__ attn_x,
    const float* __restrict__ tmx,
    unsigned short* __restrict__ shifted, unsigned short* __restrict__ xin) {
    size_t i = ((size_t)blockIdx.x * 256 + threadIdx.x) * 4;
    int n = (int)(i >> 11);
    int h = (int)(i & 2047);
    int t = n & (TT - 1);
    float4 x = *(const float4*)(hidden + i);
    float4 s;
    if (t == 0) {
        int b = n >> 12;
        s = *(const float4*)(attn_x + ((size_t)b << 11) + h);
    } else {
        s = *(const float4*)(hidden + (i - H));
    }
    float4 m = *(const float4*)(tmx + h);
    ushort4 sh, xi;
    sh.x = f2bf(s.x); sh.y = f2bf(s.y); sh.z = f2bf(s.z); sh.w = f2bf(s.w);
    xi.x = f2bf(x.x + (s.x - x.x) * m.x);
    xi.y = f2bf(x.y + (s.y - x.y) * m.y);
    xi.z = f2bf(x.z + (s.z - x.z) * m.z);
    xi.w = f2bf(x.w + (s.w - x.w) * m.w);
    *(ushort4*)(shifted + i) = sh;
    *(ushort4*)(xin + i) = xi;
}

// ---------------- transpose fp32 (R x C) -> bf16 (C x R), out ld = ldo ----
__global__ __launch_bounds__(256) void transpose_kernel(
    const float* __restrict__ in, unsigned short* __restrict__ outp,
    int R, int C, int ldo) {
    __shared__ float tile[32][33];
    int tx = threadIdx.x & 31, ty = threadIdx.x >> 5;
    int r0 = blockIdx.y * 32, c0 = blockIdx.x * 32;
    for (int i = ty; i < 32; i += 8) {
        int r = r0 + i, c = c0 + tx;
        tile[i][tx] = (r < R && c < C) ? in[(size_t)r * C + c] : 0.f;
    }
    __syncthreads();
    for (int i = ty; i < 32; i += 8) {
        int c = c0 + i, r = r0 + tx;
        if (c < C && r < R) outp[(size_t)c * ldo + r] = f2bf(tile[tx][i]);
    }
}

// ---------------- merged transpose of the 4 big weights (H x H, ldo=KC8) --
__global__ __launch_bounds__(256) void transpose4_kernel(
    const float* __restrict__ w0, const float* __restrict__ w1,
    const float* __restrict__ w2, const float* __restrict__ w3,
    unsigned short* __restrict__ d0, unsigned short* __restrict__ d1,
    unsigned short* __restrict__ d2, unsigned short* __restrict__ d3) {
    __shared__ float tile[32][33];
    int bz = blockIdx.z;
    const float* in = bz == 0 ? w0 : bz == 1 ? w1 : bz == 2 ? w2 : w3;
    unsigned short* outp = bz == 0 ? d0 : bz == 1 ? d1 : bz == 2 ? d2 : d3;
    int tx = threadIdx.x & 31, ty = threadIdx.x >> 5;
    int r0 = blockIdx.y * 32, c0 = blockIdx.x * 32;
    for (int i = ty; i < 32; i += 8)
        tile[i][tx] = in[(size_t)(r0 + i) * H + c0 + tx];
    __syncthreads();
    for (int i = ty; i < 32; i += 8)
        outp[(size_t)(c0 + i) * KC8 + r0 + tx] = f2bf(tile[tx][i]);
}

// ------- W2W stage 1 (K-split partials): part[br][ks][r][d] --------------
__global__ __launch_bounds__(256) void w2wp_kernel(
    const float* __restrict__ W2,
    const float* __restrict__ w0, const float* __restrict__ w1,
    const float* __restrict__ w2, const float* __restrict__ w3,
    const float* __restrict__ W1d,
    float* __restrict__ part) {
    const int br = blockIdx.z, ks = blockIdx.y, dblk = blockIdx.x;
    const int tid = threadIdx.x;
    const float* W; int D;
    if (br < 4) { W = br == 0 ? w0 : br == 1 ? w1 : br == 2 ? w2 : w3; D = H; }
    else        { W = W1d; D = 64; }
    const int f = br < 4 ? ((0x4213 >> (br * 4)) & 15) : 0;
    const float* W2f = W2 + (size_t)f * 32 * H;
    __shared__ float w2s[256][32];
    const int k0 = ks * 256;
    for (int idx = tid; idx < 8192; idx += 256) {
        int r = idx & 31, kk = idx >> 5;
        w2s[kk][r] = W2f[(size_t)r * H + k0 + kk];
    }
    __syncthreads();
    int d = dblk * 256 + tid;
    if (d >= D) return;
    float a[32];
#pragma unroll
    for (int r = 0; r < 32; ++r) a[r] = 0.f;
    for (int kk = 0; kk < 256; ++kk) {
        float w = W[(size_t)(k0 + kk) * D + d];
        const float4* w4 = (const float4*)w2s[kk];
#pragma unroll
        for (int rq = 0; rq < 8; ++rq) {
            float4 v = w4[rq];
            a[rq * 4 + 0] += v.x * w;
            a[rq * 4 + 1] += v.y * w;
            a[rq * 4 + 2] += v.z * w;
            a[rq * 4 + 3] += v.w * w;
        }
    }
    float* pp = part + (((size_t)br * 8 + ks) * 32) * 2048 + d;
#pragma unroll
    for (int r = 0; r < 32; ++r) pp[(size_t)r * 2048] = a[r];
}

// ------- W2W stage 2: reduce 8 partials -> bf16 Bcat cols + zero pad ------
__global__ __launch_bounds__(256) void w2wr_kernel(
    const float* __restrict__ part,
    unsigned short* __restrict__ dR, unsigned short* __restrict__ dK,
    unsigned short* __restrict__ dV, unsigned short* __restrict__ dG,
    unsigned short* __restrict__ d1) {
    int gid = blockIdx.x * 256 + threadIdx.x;     // 0..264191
    if (gid < 262144) {
        int br = gid >> 16, rem = gid & 65535;
        int r = rem >> 11, d = rem & 2047;
        float s = 0.f;
#pragma unroll
        for (int ks = 0; ks < 8; ++ks)
            s += part[(((size_t)br * 8 + ks) * 32 + r) * 2048 + d];
        unsigned short* dst = br == 0 ? dR : br == 1 ? dK : br == 2 ? dV : dG;
        dst[(size_t)d * KC8 + H + r] = f2bf(s);
        dst[(size_t)d * KC8 + H + 32 + r] = 0;    // zero pad
    } else {
        int q = gid - 262144;                      // 0..2047
        int r = q >> 6, d = q & 63;
        float s = 0.f;
#pragma unroll
        for (int ks = 0; ks < 8; ++ks)
            s += part[(((size_t)4 * 8 + ks) * 32 + r) * 2048 + d];
        d1[(size_t)d * KCAT + H + r] = f2bf(s);
    }
}

// -------- bias (merged): wave per row; bias[d] = dot(maa, W[:,d]) via Bcat rows --
__global__ __launch_bounds__(256) void bias_all_kernel(
    const unsigned short* __restrict__ bR, const unsigned short* __restrict__ bK,
    const unsigned short* __restrict__ bV, const unsigned short* __restrict__ bG,
    const unsigned short* __restrict__ b1,
    const float* __restrict__ mR, const float* __restrict__ mK,
    const float* __restrict__ mV, const float* __restrict__ mG,
    const float* __restrict__ mW,
    float* __restrict__ bias4, float* __restrict__ bias0) {
    int wave = threadIdx.x >> 6, lane = threadIdx.x & 63;
    int p = blockIdx.x * 4 + wave;          // 0..8255
    const unsigned short* src; const float* maa; float* dst;
    if (p < 8192) {
        int br = p >> 11, row = p & 2047;
        src = (br == 0 ? bR : br == 1 ? bK : br == 2 ? bV : bG) + (size_t)row * KC8;
        maa = (br == 0 ? mR : br == 1 ? mK : br == 2 ? mV : mG);
        dst = bias4 + br * H + row;
    } else {
        int q = p - 8192;
        if (q >= 64) return;
        src = b1 + (size_t)q * KCAT; maa = mW; dst = bias0 + q;
    }
    float a = 0.f;
#pragma unroll 4
    for (int i = 0; i < 32; ++i) { int h = i * 64 + lane; a += bf2f(src[h]) * maa[h]; }
    for (int s = 32; s; s >>= 1) a += __shfl_xor(a, s);
    if (lane == 0) *dst = a;
}

// ---------------- old-style MFMA GEMM core (z / tdmid) --------------------
template <int WM, int WN, int FM, int FN, int HAS_BIAS, int ACT, int OF32, int ZPAD>
__global__ __launch_bounds__(256) void gemm_kernel(
    const unsigned short* __restrict__ A, int lda,
    const unsigned short* __restrict__ A2, int lda2, int KS,
    const unsigned short* __restrict__ Bt, int ldb, int K,
    void* __restrict__ outp, int ldo, int NT,
    const float* __restrict__ bias) {
    static_assert(WM * WN == 4, "4 waves");
    constexpr int BM = WM * FM * 16;
    constexpr int BN = WN * FN * 16;
    __shared__ unsigned short As[BM * 32];
    __shared__ unsigned short Bs[BN * 32];

    const int nb = gridDim.x;
    const int bid = blockIdx.x;
    const int swz = (bid & 7) * (nb >> 3) + (bid >> 3);   // nb % 8 == 0
    const int mt = swz / NT, nt = swz % NT;
    const int m0 = mt * BM, n0 = nt * BN;

    const int tid = threadIdx.x;
    const int wave = tid >> 6, lane = tid & 63;
    const int l16 = lane & 15, kh = lane >> 4;
    const int wr = wave / WN, wc = wave % WN;

    f32x4 acc[FM][FN] = {};

    constexpr int ACH = BM * 4;   // 16B chunks in A tile
    constexpr int BCH = BN * 4;

    for (int k0 = 0; k0 < K; k0 += 32) {
#pragma unroll
        for (int i = 0; i < (ACH + 255) / 256; ++i) {
            int c = i * 256 + tid;
            if (ACH % 256 == 0 || c < ACH) {
                int row = c >> 2, ck = c & 3;
                int kk = k0 + ck * 8;
                const unsigned short* gp = (kk < KS)
                    ? A  + (size_t)(m0 + row) * lda  + kk
                    : A2 + (size_t)(m0 + row) * lda2 + (kk - KS);
                gload_lds16(gp, As + (size_t)(i * 256 + wave * 64) * 8);
            }
        }
#pragma unroll
        for (int i = 0; i < (BCH + 255) / 256; ++i) {
            int c = i * 256 + tid;
            if (BCH % 256 == 0 || c < BCH) {
                int row = c >> 2, ck = c & 3;
                gload_lds16(Bt + (size_t)(n0 + row) * ldb + k0 + ck * 8,
                            Bs + (size_t)(i * 256 + wave * 64) * 8);
            }
        }
        __syncthreads();
        bh8 av[FM], bv[FN];
#pragma unroll
        for (int mi = 0; mi < FM; ++mi)
            av[mi] = *(const bh8*)((const char*)As + (((wr * FM + mi) * 16 + l16) * 64 + kh * 16));
#pragma unroll
        for (int ni = 0; ni < FN; ++ni)
            bv[ni] = *(const bh8*)((const char*)Bs + (((wc * FN + ni) * 16 + l16) * 64 + kh * 16));
#pragma unroll
        for (int mi = 0; mi < FM; ++mi)
#pragma unroll
            for (int ni = 0; ni < FN; ++ni)
                acc[mi][ni] = __builtin_amdgcn_mfma_f32_16x16x32_bf16(
                    av[mi], bv[ni], acc[mi][ni], 0, 0, 0);
        __syncthreads();
    }

#pragma unroll
    for (int mi = 0; mi < FM; ++mi) {
#pragma unroll
        for (int ni = 0; ni < FN; ++ni) {
            int col = n0 + (wc * FN + ni) * 16 + l16;
            float bcol = HAS_BIAS ? bias[col] : 0.f;
#pragma unroll
            for (int j = 0; j < 4; ++j) {
                int row = m0 + (wr * FM + mi) * 16 + kh * 4 + j;
                float v = acc[mi][ni][j] + bcol;
                if (ACT == 1) v = v * (1.f / (1.f + __expf(-v)));
                else if (ACT == 2) v = tanhf(v);
                if (ZPAD) {
                    int br = col >> 5, cc = col & 31;
                    unsigned short* zp = (unsigned short*)outp
                        + (size_t)br * NTH64 + (size_t)row * 64 + cc;
                    zp[0] = f2bf(v);
                    zp[32] = 0;
                } else if (OF32) {
                    ((float*)outp)[(size_t)row * ldo + col] = v;
                } else {
                    ((unsigned short*)outp)[(size_t)row * ldo + col] = f2bf(v);
                }
            }
        }
    }
}

// ====== bigproj: 256x256, BK=32, 8 waves, 4-ring, distance-2, counted vmcnt
// m201-faithful DUAL-BARRIER phases: each phase = {ds-reads(this phase) ||
// 2 stage-issues -> s_barrier -> lgkmcnt(0)+sched_barrier -> setprio MFMA ->
// s_barrier}; vmcnt(4) once per tile at phase-B boundary (never 0 mid-loop).
__global__ __launch_bounds__(512, 2) void bigproj8_kernel(
    const unsigned short* __restrict__ A,      // shifted [NROWS][2048]
    const unsigned short* __restrict__ zpad,   // [5][NROWS][64] (cols 32..63 = 0)
    const unsigned short* __restrict__ bt0, const unsigned short* __restrict__ bt1,
    const unsigned short* __restrict__ bt2, const unsigned short* __restrict__ bt3,
    const float* __restrict__ bias4, float* __restrict__ out) {
    constexpr int BUFB = 32768;          // bytes per K-tile buffer (A 16K + B 16K)
    constexpr int NTK = KC8 / 32;        // 66 K-tiles; 0..63 in A, 64..65 in zpad
    __shared__ alignas(16) char lds[4 * BUFB];

    const int bid = blockIdx.x;                      // 2048 blocks
    const int swz = (bid & 7) * 256 + (bid >> 3);    // bijective XCD swizzle
    const int branch = swz >> 9;                     // 0..3 = R,K,V,G
    const int tile = swz & 511;
    const int m0 = (tile >> 3) * 256, n0 = (tile & 7) * 256;

    const unsigned short* Bt = branch == 0 ? bt0 : branch == 1 ? bt1
                             : branch == 2 ? bt2 : bt3;
    const int f = (0x4213 >> (branch * 4)) & 15;     // fidx {3,1,2,4}
    const unsigned short* Az = zpad + (size_t)f * NTH64;

    const int tid = threadIdx.x;
    const int wave = tid >> 6, lane = tid & 63;
    const int l16 = lane & 15, kh = lane >> 4;
    const int wm = wave >> 2, wn = wave & 3;         // 2M x 4N waves
    const int kh16 = kh * 16;
    const int swr = (l16 & 8) << 2;                  // read-side XOR (st_16x32)

    // ---- precomputed staging bases (byte pointers); addr = base + kt*64 ----
    const int rS = tid >> 2;                         // staging row 0..127 (j=0)
    const int kbx = ((tid & 3) * 16) ^ ((rS & 8) << 2);   // src swizzle
    const char* bA0 = (const char*)A  + (size_t)(m0 + rS) * 4096 + kbx;
    const char* bA1 = bA0 + (size_t)128 * 4096;      // j=1: rows 128..255
    const char* bz0 = (const char*)Az + (size_t)(m0 + rS) * 128 + kbx;
    const char* bz1 = bz0 + (size_t)128 * 128;
    const char* bB0 = (const char*)Bt + (size_t)(n0 + rS) * (KC8 * 2) + kbx;
    const char* bB1 = bB0 + (size_t)128 * (KC8 * 2);
    const int dA0 = wave * 1024, dA1 = 8192 + wave * 1024;

    auto stageA = [&](int kt, char* nb) {
        const char *p0, *p1;
        if (kt < 64) { size_t o = (size_t)kt * 64;        p0 = bA0 + o; p1 = bA1 + o; }
        else         { size_t o = (size_t)(kt - 64) * 64; p0 = bz0 + o; p1 = bz1 + o; }
        gload_lds16(p0, nb + dA0);
        gload_lds16(p1, nb + dA1);
    };
    auto stageB = [&](int kt, char* nb) {
        size_t o = (size_t)kt * 64;
        gload_lds16(bB0 + o, nb + 16384 + dA0);
        gload_lds16(bB1 + o, nb + 16384 + dA1);
    };

    f32x4 acc[8][4] = {};
    bh8 avlo[4], avhi[4], bv[4];

    // prologue: stage K-tiles 0 and 1; ensure tile 0 resident
    stageA(0, lds);        stageB(0, lds);
    stageA(1, lds + BUFB); stageB(1, lds + BUFB);
    asm volatile("s_waitcnt vmcnt(4)" ::: "memory");   // tile 0 complete
    __builtin_amdgcn_s_barrier();
    __builtin_amdgcn_sched_barrier(0);

    for (int t = 0; t < NTK; ++t) {
        const char* cb = lds + (t & 3) * BUFB;
        char* nb = lds + ((t + 2) & 3) * BUFB;
        const bool doSt = (t + 2) < NTK;

        // ---- phase A: reads avlo+bv (tile t) || stageA(t+2) ----
#pragma unroll
        for (int i = 0; i < 4; ++i) {
            avlo[i] = *(const bh8*)(cb + (wm * 8 + i) * 1024 + l16 * 64 + (kh16 ^ swr));
            bv[i]   = *(const bh8*)(cb + 16384 + (wn * 4 + i) * 1024 + l16 * 64 + (kh16 ^ swr));
        }
        if (doSt) stageA(t + 2, nb);
        __builtin_amdgcn_s_barrier();
        asm volatile("s_waitcnt lgkmcnt(0)" ::: "memory");
        __builtin_amdgcn_sched_barrier(0);
        __builtin_amdgcn_s_setprio(1);
#pragma unroll
        for (int mi = 0; mi < 4; ++mi)
#pragma unroll
            for (int ni = 0; ni < 4; ++ni)
                acc[mi][ni] = __builtin_amdgcn_mfma_f32_16x16x32_bf16(
                    avlo[mi], bv[ni], acc[mi][ni], 0, 0, 0);
        __builtin_amdgcn_s_setprio(0);
        __builtin_amdgcn_s_barrier();

        // ---- phase B: reads avhi || stageB(t+2); boundary vmcnt; MFMA hi ----
#pragma unroll
        for (int i = 0; i < 4; ++i)
            avhi[i] = *(const bh8*)(cb + (wm * 8 + 4 + i) * 1024 + l16 * 64 + (kh16 ^ swr));
        if (doSt) stageB(t + 2, nb);
        if (t + 1 < NTK) {
            if (doSt) asm volatile("s_waitcnt vmcnt(4)" ::: "memory");
            else      asm volatile("s_waitcnt vmcnt(0)" ::: "memory");
        }
        __builtin_amdgcn_s_barrier();
        asm volatile("s_waitcnt lgkmcnt(0)" ::: "memory");
        __builtin_amdgcn_sched_barrier(0);
        __builtin_amdgcn_s_setprio(1);
#pragma unroll
        for (int mi = 0; mi < 4; ++mi)
#pragma unroll
            for (int ni = 0; ni < 4; ++ni)
                acc[4 + mi][ni] = __builtin_amdgcn_mfma_f32_16x16x32_bf16(
                    avhi[mi], bv[ni], acc[4 + mi][ni], 0, 0, 0);
        __builtin_amdgcn_s_setprio(0);
        __builtin_amdgcn_s_barrier();
    }

    float* outp = out + (size_t)branch * NTH;
    const float* bias = bias4 + branch * H;
#pragma unroll
    for (int a = 0; a < 8; ++a) {
#pragma unroll
        for (int b = 0; b < 4; ++b) {
            int col = n0 + wn * 64 + b * 16 + l16;
            float bc = bias[col];
#pragma unroll
            for (int j = 0; j < 4; ++j) {
                int row = m0 + wm * 128 + a * 16 + kh * 4 + j;
                float v = acc[a][b][j] + bc;
                if (branch == 3) v = v * (1.f / (1.f + __expf(-v)));   // silu
                outp[(size_t)row * H + col] = v;
            }
        }
    }
}

// ------- td stage 2 (fp32 VALU): out = tdecay + tdmid(N x 64) @ W2d(64 x H) ----
__global__ __launch_bounds__(256) void td2_kernel(
    const float* __restrict__ tdmid, const float* __restrict__ W2d,
    const float* __restrict__ tdecay, float* __restrict__ outp) {
    int col = blockIdx.x * 256 + threadIdx.x;
    int row0 = blockIdx.y * 8;
    float a[8] = {0, 0, 0, 0, 0, 0, 0, 0};
    for (int r = 0; r < 64; ++r) {
        float w = W2d[(size_t)r * H + col];
#pragma unroll
        for (int j = 0; j < 8; ++j)
            a[j] += tdmid[(size_t)(row0 + j) * 64 + r] * w;
    }
    float b = tdecay[col];
#pragma unroll
    for (int j = 0; j < 8; ++j)
        outp[(size_t)(row0 + j) * H + col] = a[j] + b;
}

// ---------------- attn_x_new = hidden[:, -1]  (fp32, exact) ---------------
__global__ __launch_bounds__(256) void axnew_kernel(
    const float* __restrict__ hidden, float* __restrict__ outp) {
    int i = blockIdx.x * 256 + threadIdx.x;       // 0..8191
    int b = i >> 11, h = i & 2047;
    outp[i] = hidden[((size_t)(b * TT + (TT - 1)) << 11) + h];
}

extern "C" void kernel_launch(void* const* d_in, const int* in_sizes, int n_in,
                              void* d_out, int out_size, void* d_ws, size_t ws_size,
                              hipStream_t stream) {
    const float* hidden = (const float*)d_in[0];
    const float* attn_x = (const float*)d_in[1];
    const float* tmx    = (const float*)d_in[4];
    const float* tmaa_w = (const float*)d_in[5];
    const float* tmaa_k = (const float*)d_in[6];
    const float* tmaa_v = (const float*)d_in[7];
    const float* tmaa_r = (const float*)d_in[8];
    const float* tmaa_g = (const float*)d_in[9];
    const float* W1     = (const float*)d_in[10];   // (H,160)
    const float* W2     = (const float*)d_in[11];   // (5,32,H)
    const float* tdecay = (const float*)d_in[12];   // (1,1,H)
    const float* W1d    = (const float*)d_in[13];   // (H,64)
    const float* W2d    = (const float*)d_in[14];   // (64,H)
    const float* Wr     = (const float*)d_in[16];
    const float* Wk     = (const float*)d_in[17];
    const float* Wv     = (const float*)d_in[18];
    const float* Wg     = (const float*)d_in[19];

    float* out = (float*)d_out;     // reference outputs are float32

    char* ws = (char*)d_ws;
    size_t off = 0;
    auto alloc = [&](size_t bytes) {
        char* p = ws + off;
        off = (off + bytes + 255) & ~(size_t)255;
        return p;
    };
    unsigned short* shifted = (unsigned short*)alloc(NTH * 2);
    unsigned short* xin     = (unsigned short*)alloc(NTH * 2);
    unsigned short* zpad    = (unsigned short*)alloc(5 * NTH64 * 2);
    unsigned short* W1t     = (unsigned short*)alloc((size_t)160 * H * 2);
    unsigned short* BcatR   = (unsigned short*)alloc((size_t)H * KC8 * 2);
    unsigned short* BcatK   = (unsigned short*)alloc((size_t)H * KC8 * 2);
    unsigned short* BcatV   = (unsigned short*)alloc((size_t)H * KC8 * 2);
    unsigned short* BcatG   = (unsigned short*)alloc((size_t)H * KC8 * 2);
    unsigned short* Bcat1   = (unsigned short*)alloc((size_t)64 * KCAT * 2);
    float* tdmid            = (float*)alloc((size_t)NROWS * 64 * 4);
    float* part             = (float*)alloc((size_t)5 * 8 * 32 * 2048 * 4);
    float* bias4            = (float*)alloc(4 * H * 4);
    float* bias0            = (float*)alloc(64 * 4);

    // 1. shifted / xin
    prep_kernel<<<(unsigned)(NTH / (4 * 256)), 256, 0, stream>>>(hidden, attn_x, tmx, shifted, xin);

    // 2. fused weights: transposes + K-split low-rank fusion + biases
    transpose4_kernel<<<dim3(64, 64, 4), 256, 0, stream>>>(
        Wr, Wk, Wv, Wg, BcatR, BcatK, BcatV, BcatG);
    transpose_kernel<<<dim3(5, 64), 256, 0, stream>>>(W1, W1t, H, 160, H);
    transpose_kernel<<<dim3(2, 64), 256, 0, stream>>>(W1d, Bcat1, H, 64, KCAT);
    w2wp_kernel<<<dim3(8, 8, 5), 256, 0, stream>>>(
        W2, Wr, Wk, Wv, Wg, W1d, part);
    w2wr_kernel<<<1032, 256, 0, stream>>>(
        part, BcatR, BcatK, BcatV, BcatG, Bcat1);
    bias_all_kernel<<<2064, 256, 0, stream>>>(
        BcatR, BcatK, BcatV, BcatG, Bcat1,
        tmaa_r, tmaa_k, tmaa_v, tmaa_g, tmaa_w, bias4, bias0);

    // 3. z = tanh(xin @ W1) -> zpad [5][NROWS][64], cols 32..63 zeroed
    gemm_kernel<4, 1, 1, 10, 0, 2, 0, 1><<<256, 256, 0, stream>>>(
        xin, H, xin, H, H, W1t, H, H, zpad, 0, 1, nullptr);

    // 4. big projections (merged R,K,V,G), dual-barrier 8-phase pipelined
    bigproj8_kernel<<<2048, 512, 0, stream>>>(
        shifted, zpad, BcatR, BcatK, BcatV, BcatG, bias4, out);

    // 5. decay: tdmid = tanh([shifted | z_0] @ Bcat1^T + bias0)   (fp32 out)
    gemm_kernel<4, 1, 1, 4, 1, 2, 1, 0><<<256, 256, 0, stream>>>(
        shifted, H, zpad, 64, H, Bcat1, KCAT, KCAT,
        tdmid, 64, 1, bias0);
    //    td = time_decay + tdmid @ W2d   (fp32 VALU, register-blocked)
    td2_kernel<<<dim3(8, NROWS / 8), 256, 0, stream>>>(
        tdmid, W2d, tdecay, out + 4 * NTH);

    // 6. attn_x_new (exact fp32 copy)
    axnew_kernel<<<32, 256, 0, stream>>>(hidden, out + 5 * NTH);
}

// Round 15
// 883.921 us; speedup vs baseline: 1.0283x; 1.0283x over previous
//
#include <hip/hip_runtime.h>

#define H 2048
#define TT 4096
#define BB 4
#define NROWS (BB * TT)               // 16384
#define NTH ((size_t)NROWS * H)       // 33,554,432
#define KCAT (H + 32)                 // 2080 (decay path)
#define KC8  (H + 64)                 // 2112 (bigproj, zero-padded)
#define NTH64 ((size_t)NROWS * 64)

typedef __attribute__((ext_vector_type(8))) short bh8;
typedef __attribute__((ext_vector_type(4))) float f32x4;

__device__ inline unsigned short f2bf(float f) {
    union { float f; unsigned u; } v; v.f = f;
    unsigned r = v.u + 0x7fff + ((v.u >> 16) & 1);   // RNE
    return (unsigned short)(r >> 16);
}
__device__ inline float bf2f(unsigned short u) {
    union { unsigned u; float f; } v; v.u = ((unsigned)u) << 16; return v.f;
}
__device__ inline void gload_lds16(const void* g, void* l) {
    __builtin_amdgcn_global_load_lds(
        (const __attribute__((address_space(1))) void*)g,
        (__attribute__((address_space(3))) void*)l, 16, 0, 0);
}

// ------- prep: shifted & xin (bf16), vectorized; fuses attn_x_new copy -----
__global__ __launch_bounds__(256) void prep_kernel(
    const float* __restrict__ hidden, const float* __restrict__ attn_x,
    const float* __restrict__ tmx,
    unsigned short* __restrict__ shifted, unsigned short* __restrict__ xin,
    float* __restrict__ out5) {
    size_t i = ((size_t)blockIdx.x * 256 + threadIdx.x) * 4;
    int n = (int)(i >> 11);
    int h = (int)(i & 2047);
    int t = n & (TT - 1);
    float4 x = *(const float4*)(hidden + i);
    float4 s;
    if (t == 0) {
        int b = n >> 12;
        s = *(const float4*)(attn_x + ((size_t)b << 11) + h);
    } else {
        s = *(const float4*)(hidden + (i - H));
    }
    float4 m = *(const float4*)(tmx + h);
    ushort4 sh, xi;
    sh.x = f2bf(s.x); sh.y = f2bf(s.y); sh.z = f2bf(s.z); sh.w = f2bf(s.w);
    xi.x = f2bf(x.x + (s.x - x.x) * m.x);
    xi.y = f2bf(x.y + (s.y - x.y) * m.y);
    xi.z = f2bf(x.z + (s.z - x.z) * m.z);
    xi.w = f2bf(x.w + (s.w - x.w) * m.w);
    *(ushort4*)(shifted + i) = sh;
    *(ushort4*)(xin + i) = xi;
    if (t == TT - 1) {                 // attn_x_new = hidden[:, -1] (fp32 exact)
        int b = n >> 12;
        *(float4*)(out5 + ((size_t)b << 11) + h) = x;
    }
}

// ---------------- transpose fp32 (R x C) -> bf16 (C x R), out ld = ldo ----
__global__ __launch_bounds__(256) void transpose_kernel(
    const float* __restrict__ in, unsigned short* __restrict__ outp,
    int R, int C, int ldo) {
    __shared__ float tile[32][33];
    int tx = threadIdx.x & 31, ty = threadIdx.x >> 5;
    int r0 = blockIdx.y * 32, c0 = blockIdx.x * 32;
    for (int i = ty; i < 32; i += 8) {
        int r = r0 + i, c = c0 + tx;
        tile[i][tx] = (r < R && c < C) ? in[(size_t)r * C + c] : 0.f;
    }
    __syncthreads();
    for (int i = ty; i < 32; i += 8) {
        int c = c0 + i, r = r0 + tx;
        if (c < C && r < R) outp[(size_t)c * ldo + r] = f2bf(tile[tx][i]);
    }
}

// ---------------- merged transpose of the 4 big weights (H x H, ldo=KC8) --
__global__ __launch_bounds__(256) void transpose4_kernel(
    const float* __restrict__ w0, const float* __restrict__ w1,
    const float* __restrict__ w2, const float* __restrict__ w3,
    unsigned short* __restrict__ d0, unsigned short* __restrict__ d1,
    unsigned short* __restrict__ d2, unsigned short* __restrict__ d3) {
    __shared__ float tile[32][33];
    int bz = blockIdx.z;
    const float* in = bz == 0 ? w0 : bz == 1 ? w1 : bz == 2 ? w2 : w3;
    unsigned short* outp = bz == 0 ? d0 : bz == 1 ? d1 : bz == 2 ? d2 : d3;
    int tx = threadIdx.x & 31, ty = threadIdx.x >> 5;
    int r0 = blockIdx.y * 32, c0 = blockIdx.x * 32;
    for (int i = ty; i < 32; i += 8)
        tile[i][tx] = in[(size_t)(r0 + i) * H + c0 + tx];
    __syncthreads();
    for (int i = ty; i < 32; i += 8)
        outp[(size_t)(c0 + i) * KC8 + r0 + tx] = f2bf(tile[tx][i]);
}

// ------- W2W stage 1 (K-split partials): part[br][ks][r][d] --------------
__global__ __launch_bounds__(256) void w2wp_kernel(
    const float* __restrict__ W2,
    const float* __restrict__ w0, const float* __restrict__ w1,
    const float* __restrict__ w2, const float* __restrict__ w3,
    const float* __restrict__ W1d,
    float* __restrict__ part) {
    const int br = blockIdx.z, ks = blockIdx.y, dblk = blockIdx.x;
    const int tid = threadIdx.x;
    const float* W; int D;
    if (br < 4) { W = br == 0 ? w0 : br == 1 ? w1 : br == 2 ? w2 : w3; D = H; }
    else        { W = W1d; D = 64; }
    const int f = br < 4 ? ((0x4213 >> (br * 4)) & 15) : 0;
    const float* W2f = W2 + (size_t)f * 32 * H;
    __shared__ float w2s[256][32];
    const int k0 = ks * 256;
    for (int idx = tid; idx < 8192; idx += 256) {
        int r = idx & 31, kk = idx >> 5;
        w2s[kk][r] = W2f[(size_t)r * H + k0 + kk];
    }
    __syncthreads();
    int d = dblk * 256 + tid;
    if (d >= D) return;
    float a[32];
#pragma unroll
    for (int r = 0; r < 32; ++r) a[r] = 0.f;
    for (int kk = 0; kk < 256; ++kk) {
        float w = W[(size_t)(k0 + kk) * D + d];
        const float4* w4 = (const float4*)w2s[kk];
#pragma unroll
        for (int rq = 0; rq < 8; ++rq) {
            float4 v = w4[rq];
            a[rq * 4 + 0] += v.x * w;
            a[rq * 4 + 1] += v.y * w;
            a[rq * 4 + 2] += v.z * w;
            a[rq * 4 + 3] += v.w * w;
        }
    }
    float* pp = part + (((size_t)br * 8 + ks) * 32) * 2048 + d;
#pragma unroll
    for (int r = 0; r < 32; ++r) pp[(size_t)r * 2048] = a[r];
}

// ------- W2W stage 2: reduce 8 partials -> bf16 Bcat cols + zero pad ------
__global__ __launch_bounds__(256) void w2wr_kernel(
    const float* __restrict__ part,
    unsigned short* __restrict__ dR, unsigned short* __restrict__ dK,
    unsigned short* __restrict__ dV, unsigned short* __restrict__ dG,
    unsigned short* __restrict__ d1) {
    int gid = blockIdx.x * 256 + threadIdx.x;     // 0..264191
    if (gid < 262144) {
        int br = gid >> 16, rem = gid & 65535;
        int r = rem >> 11, d = rem & 2047;
        float s = 0.f;
#pragma unroll
        for (int ks = 0; ks < 8; ++ks)
            s += part[(((size_t)br * 8 + ks) * 32 + r) * 2048 + d];
        unsigned short* dst = br == 0 ? dR : br == 1 ? dK : br == 2 ? dV : dG;
        dst[(size_t)d * KC8 + H + r] = f2bf(s);
        dst[(size_t)d * KC8 + H + 32 + r] = 0;    // zero pad
    } else {
        int q = gid - 262144;                      // 0..2047
        int r = q >> 6, d = q & 63;
        float s = 0.f;
#pragma unroll
        for (int ks = 0; ks < 8; ++ks)
            s += part[(((size_t)4 * 8 + ks) * 32 + r) * 2048 + d];
        d1[(size_t)d * KCAT + H + r] = f2bf(s);
    }
}

// -------- bias (merged): wave per row; bias[d] = dot(maa, W[:,d]) via Bcat rows --
__global__ __launch_bounds__(256) void bias_all_kernel(
    const unsigned short* __restrict__ bR, const unsigned short* __restrict__ bK,
    const unsigned short* __restrict__ bV, const unsigned short* __restrict__ bG,
    const unsigned short* __restrict__ b1,
    const float* __restrict__ mR, const float* __restrict__ mK,
    const float* __restrict__ mV, const float* __restrict__ mG,
    const float* __restrict__ mW,
    float* __restrict__ bias4, float* __restrict__ bias0) {
    int wave = threadIdx.x >> 6, lane = threadIdx.x & 63;
    int p = blockIdx.x * 4 + wave;          // 0..8255
    const unsigned short* src; const float* maa; float* dst;
    if (p < 8192) {
        int br = p >> 11, row = p & 2047;
        src = (br == 0 ? bR : br == 1 ? bK : br == 2 ? bV : bG) + (size_t)row * KC8;
        maa = (br == 0 ? mR : br == 1 ? mK : br == 2 ? mV : mG);
        dst = bias4 + br * H + row;
    } else {
        int q = p - 8192;
        if (q >= 64) return;
        src = b1 + (size_t)q * KCAT; maa = mW; dst = bias0 + q;
    }
    float a = 0.f;
#pragma unroll 4
    for (int i = 0; i < 32; ++i) { int h = i * 64 + lane; a += bf2f(src[h]) * maa[h]; }
    for (int s = 32; s; s >>= 1) a += __shfl_xor(a, s);
    if (lane == 0) *dst = a;
}

// ---------------- old-style MFMA GEMM core (z / tdmid) --------------------
template <int WM, int WN, int FM, int FN, int HAS_BIAS, int ACT, int OF32, int ZPAD>
__global__ __launch_bounds__(256) void gemm_kernel(
    const unsigned short* __restrict__ A, int lda,
    const unsigned short* __restrict__ A2, int lda2, int KS,
    const unsigned short* __restrict__ Bt, int ldb, int K,
    void* __restrict__ outp, int ldo, int NT,
    const float* __restrict__ bias) {
    static_assert(WM * WN == 4, "4 waves");
    constexpr int BM = WM * FM * 16;
    constexpr int BN = WN * FN * 16;
    __shared__ unsigned short As[BM * 32];
    __shared__ unsigned short Bs[BN * 32];

    const int nb = gridDim.x;
    const int bid = blockIdx.x;
    const int swz = (bid & 7) * (nb >> 3) + (bid >> 3);   // nb % 8 == 0
    const int mt = swz / NT, nt = swz % NT;
    const int m0 = mt * BM, n0 = nt * BN;

    const int tid = threadIdx.x;
    const int wave = tid >> 6, lane = tid & 63;
    const int l16 = lane & 15, kh = lane >> 4;
    const int wr = wave / WN, wc = wave % WN;

    f32x4 acc[FM][FN] = {};

    constexpr int ACH = BM * 4;   // 16B chunks in A tile
    constexpr int BCH = BN * 4;

    for (int k0 = 0; k0 < K; k0 += 32) {
#pragma unroll
        for (int i = 0; i < (ACH + 255) / 256; ++i) {
            int c = i * 256 + tid;
            if (ACH % 256 == 0 || c < ACH) {
                int row = c >> 2, ck = c & 3;
                int kk = k0 + ck * 8;
                const unsigned short* gp = (kk < KS)
                    ? A  + (size_t)(m0 + row) * lda  + kk
                    : A2 + (size_t)(m0 + row) * lda2 + (kk - KS);
                gload_lds16(gp, As + (size_t)(i * 256 + wave * 64) * 8);
            }
        }
#pragma unroll
        for (int i = 0; i < (BCH + 255) / 256; ++i) {
            int c = i * 256 + tid;
            if (BCH % 256 == 0 || c < BCH) {
                int row = c >> 2, ck = c & 3;
                gload_lds16(Bt + (size_t)(n0 + row) * ldb + k0 + ck * 8,
                            Bs + (size_t)(i * 256 + wave * 64) * 8);
            }
        }
        __syncthreads();
        bh8 av[FM], bv[FN];
#pragma unroll
        for (int mi = 0; mi < FM; ++mi)
            av[mi] = *(const bh8*)((const char*)As + (((wr * FM + mi) * 16 + l16) * 64 + kh * 16));
#pragma unroll
        for (int ni = 0; ni < FN; ++ni)
            bv[ni] = *(const bh8*)((const char*)Bs + (((wc * FN + ni) * 16 + l16) * 64 + kh * 16));
#pragma unroll
        for (int mi = 0; mi < FM; ++mi)
#pragma unroll
            for (int ni = 0; ni < FN; ++ni)
                acc[mi][ni] = __builtin_amdgcn_mfma_f32_16x16x32_bf16(
                    av[mi], bv[ni], acc[mi][ni], 0, 0, 0);
        __syncthreads();
    }

#pragma unroll
    for (int mi = 0; mi < FM; ++mi) {
#pragma unroll
        for (int ni = 0; ni < FN; ++ni) {
            int col = n0 + (wc * FN + ni) * 16 + l16;
            float bcol = HAS_BIAS ? bias[col] : 0.f;
#pragma unroll
            for (int j = 0; j < 4; ++j) {
                int row = m0 + (wr * FM + mi) * 16 + kh * 4 + j;
                float v = acc[mi][ni][j] + bcol;
                if (ACT == 1) v = v * (1.f / (1.f + __expf(-v)));
                else if (ACT == 2) v = tanhf(v);
                if (ZPAD) {
                    int br = col >> 5, cc = col & 31;
                    unsigned short* zp = (unsigned short*)outp
                        + (size_t)br * NTH64 + (size_t)row * 64 + cc;
                    zp[0] = f2bf(v);
                    zp[32] = 0;
                } else if (OF32) {
                    ((float*)outp)[(size_t)row * ldo + col] = v;
                } else {
                    ((unsigned short*)outp)[(size_t)row * ldo + col] = f2bf(v);
                }
            }
        }
    }
}

// ====== bigproj (round-7 verbatim, best measured: 534us, MfmaUtil 50%) =====
// 256x256 tile, BK=32, 8 waves (2Mx4N), per-wave 128x64; 4-deep LDS ring,
// prefetch distance 2 K-tiles, ONE barrier per K-tile, software-pipelined
// LDS->VGPR reads, incremental staging bases (addr = base + kt*64).
__global__ __launch_bounds__(512, 2) void bigproj8_kernel(
    const unsigned short* __restrict__ A,      // shifted [NROWS][2048]
    const unsigned short* __restrict__ zpad,   // [5][NROWS][64] (cols 32..63 = 0)
    const unsigned short* __restrict__ bt0, const unsigned short* __restrict__ bt1,
    const unsigned short* __restrict__ bt2, const unsigned short* __restrict__ bt3,
    const float* __restrict__ bias4, float* __restrict__ out) {
    constexpr int BUFB = 32768;          // bytes per K-tile buffer (A 16K + B 16K)
    constexpr int NTK = KC8 / 32;        // 66 K-tiles; 0..63 in A, 64..65 in zpad
    __shared__ alignas(16) char lds[4 * BUFB];

    const int bid = blockIdx.x;                      // 2048 blocks
    const int swz = (bid & 7) * 256 + (bid >> 3);    // bijective XCD swizzle
    const int branch = swz >> 9;                     // 0..3 = R,K,V,G
    const int tile = swz & 511;
    const int m0 = (tile >> 3) * 256, n0 = (tile & 7) * 256;

    const unsigned short* Bt = branch == 0 ? bt0 : branch == 1 ? bt1
                             : branch == 2 ? bt2 : bt3;
    const int f = (0x4213 >> (branch * 4)) & 15;     // fidx {3,1,2,4}
    const unsigned short* Az = zpad + (size_t)f * NTH64;

    const int tid = threadIdx.x;
    const int wave = tid >> 6, lane = tid & 63;
    const int l16 = lane & 15, kh = lane >> 4;
    const int wm = wave >> 2, wn = wave & 3;         // 2M x 4N waves
    const int kh16 = kh * 16;
    const int swr = (l16 & 8) << 2;                  // read-side XOR (st_16x32)

    // ---- precomputed staging bases (byte pointers); addr = base + kt*64 ----
    const int rS = tid >> 2;                         // staging row 0..127 (j=0)
    const int kbx = ((tid & 3) * 16) ^ ((rS & 8) << 2);   // src swizzle, j-invariant
    const char* bA0 = (const char*)A  + (size_t)(m0 + rS) * 4096 + kbx;
    const char* bA1 = bA0 + (size_t)128 * 4096;      // j=1: rows 128..255
    const char* bz0 = (const char*)Az + (size_t)(m0 + rS) * 128 + kbx;
    const char* bz1 = bz0 + (size_t)128 * 128;
    const char* bB0 = (const char*)Bt + (size_t)(n0 + rS) * (KC8 * 2) + kbx;
    const char* bB1 = bB0 + (size_t)128 * (KC8 * 2);
    const int dA0 = wave * 1024, dA1 = 8192 + wave * 1024;

    auto stageA = [&](int kt, char* nb) {
        const char *p0, *p1;
        if (kt < 64) { size_t o = (size_t)kt * 64;        p0 = bA0 + o; p1 = bA1 + o; }
        else         { size_t o = (size_t)(kt - 64) * 64; p0 = bz0 + o; p1 = bz1 + o; }
        gload_lds16(p0, nb + dA0);
        gload_lds16(p1, nb + dA1);
    };
    auto stageB = [&](int kt, char* nb) {
        size_t o = (size_t)kt * 64;
        gload_lds16(bB0 + o, nb + 16384 + dA0);
        gload_lds16(bB1 + o, nb + 16384 + dA1);
    };

    f32x4 acc[8][4] = {};
    bh8 avlo[4], avhi[4], bvA[4], bvB[4];

    // prologue: stage K-tiles 0 and 1; read tile 0's phase-A fragments
    stageA(0, lds);        stageB(0, lds);
    stageA(1, lds + BUFB); stageB(1, lds + BUFB);
    asm volatile("s_waitcnt vmcnt(4)" ::: "memory");   // tile 0 complete
    __builtin_amdgcn_s_barrier();
    __builtin_amdgcn_sched_barrier(0);
#pragma unroll
    for (int i = 0; i < 4; ++i) {
        avlo[i] = *(const bh8*)(lds + (wm * 8 + i) * 1024 + l16 * 64 + (kh16 ^ swr));
        bvA[i]  = *(const bh8*)(lds + 16384 + (wn * 4 + i) * 1024 + l16 * 64 + (kh16 ^ swr));
    }

    auto tile_step = [&](int t, bh8 (&bvC)[4], bh8 (&bvN)[4]) {
        const char* Ab = lds + (t & 3) * BUFB;
        char* nb = lds + ((t + 2) & 3) * BUFB;
        const bool doSt = (t + 2) < NTK;

        // ---- phase A: issue avhi reads + stageA, then MFMA lo ----
#pragma unroll
        for (int i = 0; i < 4; ++i)
            avhi[i] = *(const bh8*)(Ab + (wm * 8 + 4 + i) * 1024 + l16 * 64 + (kh16 ^ swr));
        if (doSt) stageA(t + 2, nb);
        __builtin_amdgcn_s_setprio(1);
#pragma unroll
        for (int mi = 0; mi < 4; ++mi)
#pragma unroll
            for (int ni = 0; ni < 4; ++ni)
                acc[mi][ni] = __builtin_amdgcn_mfma_f32_16x16x32_bf16(
                    avlo[mi], bvC[ni], acc[mi][ni], 0, 0, 0);
        __builtin_amdgcn_s_setprio(0);

        // ---- phase B: stageB, tile-boundary sync, issue t+1 reads, MFMA hi --
        if (doSt) stageB(t + 2, nb);
        if (t + 1 < NTK) {
            if (doSt) asm volatile("s_waitcnt vmcnt(4)" ::: "memory");
            else      asm volatile("s_waitcnt vmcnt(0)" ::: "memory");
            __builtin_amdgcn_s_barrier();
            __builtin_amdgcn_sched_barrier(0);
            const char* Ab1 = lds + ((t + 1) & 3) * BUFB;
#pragma unroll
            for (int i = 0; i < 4; ++i) {
                avlo[i] = *(const bh8*)(Ab1 + (wm * 8 + i) * 1024 + l16 * 64 + (kh16 ^ swr));
                bvN[i]  = *(const bh8*)(Ab1 + 16384 + (wn * 4 + i) * 1024 + l16 * 64 + (kh16 ^ swr));
            }
        }
        __builtin_amdgcn_s_setprio(1);
#pragma unroll
        for (int mi = 0; mi < 4; ++mi)
#pragma unroll
            for (int ni = 0; ni < 4; ++ni)
                acc[4 + mi][ni] = __builtin_amdgcn_mfma_f32_16x16x32_bf16(
                    avhi[mi], bvC[ni], acc[4 + mi][ni], 0, 0, 0);
        __builtin_amdgcn_s_setprio(0);
    };

    for (int t = 0; t < NTK; t += 2) {
        tile_step(t,     bvA, bvB);
        tile_step(t + 1, bvB, bvA);
    }

    float* outp = out + (size_t)branch * NTH;
    const float* bias = bias4 + branch * H;
#pragma unroll
    for (int a = 0; a < 8; ++a) {
#pragma unroll
        for (int b = 0; b < 4; ++b) {
            int col = n0 + wn * 64 + b * 16 + l16;
            float bc = bias[col];
#pragma unroll
            for (int j = 0; j < 4; ++j) {
                int row = m0 + wm * 128 + a * 16 + kh * 4 + j;
                float v = acc[a][b][j] + bc;
                if (branch == 3) v = v * (1.f / (1.f + __expf(-v)));   // silu
                outp[(size_t)row * H + col] = v;
            }
        }
    }
}

// ------- td stage 2 (fp32 VALU): out = tdecay + tdmid(N x 64) @ W2d(64 x H) ----
__global__ __launch_bounds__(256) void td2_kernel(
    const float* __restrict__ tdmid, const float* __restrict__ W2d,
    const float* __restrict__ tdecay, float* __restrict__ outp) {
    int col = blockIdx.x * 256 + threadIdx.x;
    int row0 = blockIdx.y * 8;
    float a[8] = {0, 0, 0, 0, 0, 0, 0, 0};
    for (int r = 0; r < 64; ++r) {
        float w = W2d[(size_t)r * H + col];
#pragma unroll
        for (int j = 0; j < 8; ++j)
            a[j] += tdmid[(size_t)(row0 + j) * 64 + r] * w;
    }
    float b = tdecay[col];
#pragma unroll
    for (int j = 0; j < 8; ++j)
        outp[(size_t)(row0 + j) * H + col] = a[j] + b;
}

extern "C" void kernel_launch(void* const* d_in, const int* in_sizes, int n_in,
                              void* d_out, int out_size, void* d_ws, size_t ws_size,
                              hipStream_t stream) {
    const float* hidden = (const float*)d_in[0];
    const float* attn_x = (const float*)d_in[1];
    const float* tmx    = (const float*)d_in[4];
    const float* tmaa_w = (const float*)d_in[5];
    const float* tmaa_k = (const float*)d_in[6];
    const float* tmaa_v = (const float*)d_in[7];
    const float* tmaa_r = (const float*)d_in[8];
    const float* tmaa_g = (const float*)d_in[9];
    const float* W1     = (const float*)d_in[10];   // (H,160)
    const float* W2     = (const float*)d_in[11];   // (5,32,H)
    const float* tdecay = (const float*)d_in[12];   // (1,1,H)
    const float* W1d    = (const float*)d_in[13];   // (H,64)
    const float* W2d    = (const float*)d_in[14];   // (64,H)
    const float* Wr     = (const float*)d_in[16];
    const float* Wk     = (const float*)d_in[17];
    const float* Wv     = (const float*)d_in[18];
    const float* Wg     = (const float*)d_in[19];

    float* out = (float*)d_out;     // reference outputs are float32

    char* ws = (char*)d_ws;
    size_t off = 0;
    auto alloc = [&](size_t bytes) {
        char* p = ws + off;
        off = (off + bytes + 255) & ~(size_t)255;
        return p;
    };
    unsigned short* shifted = (unsigned short*)alloc(NTH * 2);
    unsigned short* xin     = (unsigned short*)alloc(NTH * 2);
    unsigned short* zpad    = (unsigned short*)alloc(5 * NTH64 * 2);
    unsigned short* W1t     = (unsigned short*)alloc((size_t)160 * H * 2);
    unsigned short* BcatR   = (unsigned short*)alloc((size_t)H * KC8 * 2);
    unsigned short* BcatK   = (unsigned short*)alloc((size_t)H * KC8 * 2);
    unsigned short* BcatV   = (unsigned short*)alloc((size_t)H * KC8 * 2);
    unsigned short* BcatG   = (unsigned short*)alloc((size_t)H * KC8 * 2);
    unsigned short* Bcat1   = (unsigned short*)alloc((size_t)64 * KCAT * 2);
    float* tdmid            = (float*)alloc((size_t)NROWS * 64 * 4);
    float* part             = (float*)alloc((size_t)5 * 8 * 32 * 2048 * 4);
    float* bias4            = (float*)alloc(4 * H * 4);
    float* bias0            = (float*)alloc(64 * 4);

    // 1. shifted / xin (+ fused attn_x_new copy)
    prep_kernel<<<(unsigned)(NTH / (4 * 256)), 256, 0, stream>>>(
        hidden, attn_x, tmx, shifted, xin, out + 5 * NTH);

    // 2. fused weights: transposes + K-split low-rank fusion + biases
    transpose4_kernel<<<dim3(64, 64, 4), 256, 0, stream>>>(
        Wr, Wk, Wv, Wg, BcatR, BcatK, BcatV, BcatG);
    transpose_kernel<<<dim3(5, 64), 256, 0, stream>>>(W1, W1t, H, 160, H);
    transpose_kernel<<<dim3(2, 64), 256, 0, stream>>>(W1d, Bcat1, H, 64, KCAT);
    w2wp_kernel<<<dim3(8, 8, 5), 256, 0, stream>>>(
        W2, Wr, Wk, Wv, Wg, W1d, part);
    w2wr_kernel<<<1032, 256, 0, stream>>>(
        part, BcatR, BcatK, BcatV, BcatG, Bcat1);
    bias_all_kernel<<<2064, 256, 0, stream>>>(
        BcatR, BcatK, BcatV, BcatG, Bcat1,
        tmaa_r, tmaa_k, tmaa_v, tmaa_g, tmaa_w, bias4, bias0);

    // 3. z = tanh(xin @ W1) -> zpad [5][NROWS][64], cols 32..63 zeroed
    gemm_kernel<4, 1, 1, 10, 0, 2, 0, 1><<<256, 256, 0, stream>>>(
        xin, H, xin, H, H, W1t, H, H, zpad, 0, 1, nullptr);

    // 4. big projections (merged R,K,V,G), round-7 4-ring pipelined
    bigproj8_kernel<<<2048, 512, 0, stream>>>(
        shifted, zpad, BcatR, BcatK, BcatV, BcatG, bias4, out);

    // 5. decay: tdmid = tanh([shifted | z_0] @ Bcat1^T + bias0)   (fp32 out)
    gemm_kernel<4, 1, 1, 4, 1, 2, 1, 0><<<256, 256, 0, stream>>>(
        shifted, H, zpad, 64, H, Bcat1, KCAT, KCAT,
        tdmid, 64, 1, bias0);
    //    td = time_decay + tdmid @ W2d   (fp32 VALU, register-blocked)
    td2_kernel<<<dim3(8, NROWS / 8), 256, 0, stream>>>(
        tdmid, W2d, tdecay, out + 4 * NTH);
}

// Round 16
// 853.591 us; speedup vs baseline: 1.0648x; 1.0355x over previous
//
#include <hip/hip_runtime.h>

#define H 2048
#define TT 4096
#define BB 4
#define NROWS (BB * TT)               // 16384
#define NTH ((size_t)NROWS * H)       // 33,554,432
#define KCAT (H + 32)                 // 2080 (decay path)
#define KC8  (H + 64)                 // 2112 (bigproj, zero-padded)
#define NTH64 ((size_t)NROWS * 64)

typedef __attribute__((ext_vector_type(8))) short bh8;
typedef __attribute__((ext_vector_type(4))) float f32x4;

__device__ inline unsigned short f2bf(float f) {
    union { float f; unsigned u; } v; v.f = f;
    unsigned r = v.u + 0x7fff + ((v.u >> 16) & 1);   // RNE
    return (unsigned short)(r >> 16);
}
__device__ inline float bf2f(unsigned short u) {
    union { unsigned u; float f; } v; v.u = ((unsigned)u) << 16; return v.f;
}
__device__ inline void gload_lds16(const void* g, void* l) {
    __builtin_amdgcn_global_load_lds(
        (const __attribute__((address_space(1))) void*)g,
        (__attribute__((address_space(3))) void*)l, 16, 0, 0);
}

// ------- prep: shifted & xin (bf16), vectorized; fuses attn_x_new copy -----
__global__ __launch_bounds__(256) void prep_kernel(
    const float* __restrict__ hidden, const float* __restrict__ attn_x,
    const float* __restrict__ tmx,
    unsigned short* __restrict__ shifted, unsigned short* __restrict__ xin,
    float* __restrict__ out5) {
    size_t i = ((size_t)blockIdx.x * 256 + threadIdx.x) * 4;
    int n = (int)(i >> 11);
    int h = (int)(i & 2047);
    int t = n & (TT - 1);
    float4 x = *(const float4*)(hidden + i);
    float4 s;
    if (t == 0) {
        int b = n >> 12;
        s = *(const float4*)(attn_x + ((size_t)b << 11) + h);
    } else {
        s = *(const float4*)(hidden + (i - H));
    }
    float4 m = *(const float4*)(tmx + h);
    ushort4 sh, xi;
    sh.x = f2bf(s.x); sh.y = f2bf(s.y); sh.z = f2bf(s.z); sh.w = f2bf(s.w);
    xi.x = f2bf(x.x + (s.x - x.x) * m.x);
    xi.y = f2bf(x.y + (s.y - x.y) * m.y);
    xi.z = f2bf(x.z + (s.z - x.z) * m.z);
    xi.w = f2bf(x.w + (s.w - x.w) * m.w);
    *(ushort4*)(shifted + i) = sh;
    *(ushort4*)(xin + i) = xi;
    if (t == TT - 1) {                 // attn_x_new = hidden[:, -1] (fp32 exact)
        int b = n >> 12;
        *(float4*)(out5 + ((size_t)b << 11) + h) = x;
    }
}

// ---------------- transpose fp32 (R x C) -> bf16 (C x R), out ld = ldo ----
__global__ __launch_bounds__(256) void transpose_kernel(
    const float* __restrict__ in, unsigned short* __restrict__ outp,
    int R, int C, int ldo) {
    __shared__ float tile[32][33];
    int tx = threadIdx.x & 31, ty = threadIdx.x >> 5;
    int r0 = blockIdx.y * 32, c0 = blockIdx.x * 32;
    for (int i = ty; i < 32; i += 8) {
        int r = r0 + i, c = c0 + tx;
        tile[i][tx] = (r < R && c < C) ? in[(size_t)r * C + c] : 0.f;
    }
    __syncthreads();
    for (int i = ty; i < 32; i += 8) {
        int c = c0 + i, r = r0 + tx;
        if (c < C && r < R) outp[(size_t)c * ldo + r] = f2bf(tile[tx][i]);
    }
}

// ---------------- merged transpose of the 4 big weights (H x H, ldo=KC8) --
__global__ __launch_bounds__(256) void transpose4_kernel(
    const float* __restrict__ w0, const float* __restrict__ w1,
    const float* __restrict__ w2, const float* __restrict__ w3,
    unsigned short* __restrict__ d0, unsigned short* __restrict__ d1,
    unsigned short* __restrict__ d2, unsigned short* __restrict__ d3) {
    __shared__ float tile[32][33];
    int bz = blockIdx.z;
    const float* in = bz == 0 ? w0 : bz == 1 ? w1 : bz == 2 ? w2 : w3;
    unsigned short* outp = bz == 0 ? d0 : bz == 1 ? d1 : bz == 2 ? d2 : d3;
    int tx = threadIdx.x & 31, ty = threadIdx.x >> 5;
    int r0 = blockIdx.y * 32, c0 = blockIdx.x * 32;
    for (int i = ty; i < 32; i += 8)
        tile[i][tx] = in[(size_t)(r0 + i) * H + c0 + tx];
    __syncthreads();
    for (int i = ty; i < 32; i += 8)
        outp[(size_t)(c0 + i) * KC8 + r0 + tx] = f2bf(tile[tx][i]);
}

// ------- W2W stage 1 (K-split partials): part[br][ks][r][d], r=32 is bias --
__global__ __launch_bounds__(256) void w2wp_kernel(
    const float* __restrict__ W2,
    const float* __restrict__ w0, const float* __restrict__ w1,
    const float* __restrict__ w2, const float* __restrict__ w3,
    const float* __restrict__ W1d,
    const float* __restrict__ mR, const float* __restrict__ mK,
    const float* __restrict__ mV, const float* __restrict__ mG,
    const float* __restrict__ mW,
    float* __restrict__ part) {
    const int br = blockIdx.z, ks = blockIdx.y, dblk = blockIdx.x;
    const int tid = threadIdx.x;
    const float* W; int D; const float* maa;
    if (br < 4) {
        W = br == 0 ? w0 : br == 1 ? w1 : br == 2 ? w2 : w3; D = H;
        maa = br == 0 ? mR : br == 1 ? mK : br == 2 ? mV : mG;
    } else { W = W1d; D = 64; maa = mW; }
    const int f = br < 4 ? ((0x4213 >> (br * 4)) & 15) : 0;
    const float* W2f = W2 + (size_t)f * 32 * H;
    __shared__ float w2s[256][33];       // rows 0..31 = W2f, row 32 = maa
    const int k0 = ks * 256;
#pragma unroll
    for (int r = 0; r < 33; ++r)
        w2s[tid][r] = (r < 32) ? W2f[(size_t)r * H + k0 + tid] : maa[k0 + tid];
    __syncthreads();
    int d = dblk * 256 + tid;
    if (d >= D) return;
    float a[33];
#pragma unroll
    for (int r = 0; r < 33; ++r) a[r] = 0.f;
    for (int kk = 0; kk < 256; ++kk) {
        float w = W[(size_t)(k0 + kk) * D + d];
        const float* ws2 = w2s[kk];
#pragma unroll
        for (int r = 0; r < 33; ++r) a[r] += ws2[r] * w;
    }
    float* pp = part + (((size_t)br * 8 + ks) * 33) * 2048 + d;
#pragma unroll
    for (int r = 0; r < 33; ++r) pp[(size_t)r * 2048] = a[r];
}

// --- W2W stage 2: reduce partials -> bf16 Bcat cols + zero pad + fp32 bias --
__global__ __launch_bounds__(256) void w2wr_kernel(
    const float* __restrict__ part,
    unsigned short* __restrict__ dR, unsigned short* __restrict__ dK,
    unsigned short* __restrict__ dV, unsigned short* __restrict__ dG,
    unsigned short* __restrict__ d1,
    float* __restrict__ bias4, float* __restrict__ bias0) {
    int gid = blockIdx.x * 256 + threadIdx.x;
    if (gid < 262144) {                           // Bcat R/K/V/G low-rank cols
        int br = gid >> 16, rem = gid & 65535;
        int r = rem >> 11, d = rem & 2047;
        float s = 0.f;
#pragma unroll
        for (int ks = 0; ks < 8; ++ks)
            s += part[(((size_t)br * 8 + ks) * 33 + r) * 2048 + d];
        unsigned short* dst = br == 0 ? dR : br == 1 ? dK : br == 2 ? dV : dG;
        dst[(size_t)d * KC8 + H + r] = f2bf(s);
        dst[(size_t)d * KC8 + H + 32 + r] = 0;    // zero pad
    } else if (gid < 264192) {                    // Bcat1 low-rank cols
        int q = gid - 262144;                      // 0..2047
        int r = q >> 6, d = q & 63;
        float s = 0.f;
#pragma unroll
        for (int ks = 0; ks < 8; ++ks)
            s += part[(((size_t)4 * 8 + ks) * 33 + r) * 2048 + d];
        d1[(size_t)d * KCAT + H + r] = f2bf(s);
    } else if (gid < 272384) {                    // bias4 (fp32)
        int q = gid - 264192;                      // 0..8191
        int br = q >> 11, d = q & 2047;
        float s = 0.f;
#pragma unroll
        for (int ks = 0; ks < 8; ++ks)
            s += part[(((size_t)br * 8 + ks) * 33 + 32) * 2048 + d];
        bias4[br * H + d] = s;
    } else if (gid < 272448) {                    // bias0 (fp32)
        int d = gid - 272384;                      // 0..63
        float s = 0.f;
#pragma unroll
        for (int ks = 0; ks < 8; ++ks)
            s += part[(((size_t)4 * 8 + ks) * 33 + 32) * 2048 + d];
        bias0[d] = s;
    }
}

// ---------------- old-style MFMA GEMM core (z) ----------------------------
template <int WM, int WN, int FM, int FN, int HAS_BIAS, int ACT, int OF32, int ZPAD>
__global__ __launch_bounds__(256) void gemm_kernel(
    const unsigned short* __restrict__ A, int lda,
    const unsigned short* __restrict__ A2, int lda2, int KS,
    const unsigned short* __restrict__ Bt, int ldb, int K,
    void* __restrict__ outp, int ldo, int NT,
    const float* __restrict__ bias) {
    static_assert(WM * WN == 4, "4 waves");
    constexpr int BM = WM * FM * 16;
    constexpr int BN = WN * FN * 16;
    __shared__ unsigned short As[BM * 32];
    __shared__ unsigned short Bs[BN * 32];

    const int nb = gridDim.x;
    const int bid = blockIdx.x;
    const int swz = (bid & 7) * (nb >> 3) + (bid >> 3);   // nb % 8 == 0
    const int mt = swz / NT, nt = swz % NT;
    const int m0 = mt * BM, n0 = nt * BN;

    const int tid = threadIdx.x;
    const int wave = tid >> 6, lane = tid & 63;
    const int l16 = lane & 15, kh = lane >> 4;
    const int wr = wave / WN, wc = wave % WN;

    f32x4 acc[FM][FN] = {};

    constexpr int ACH = BM * 4;   // 16B chunks in A tile
    constexpr int BCH = BN * 4;

    for (int k0 = 0; k0 < K; k0 += 32) {
#pragma unroll
        for (int i = 0; i < (ACH + 255) / 256; ++i) {
            int c = i * 256 + tid;
            if (ACH % 256 == 0 || c < ACH) {
                int row = c >> 2, ck = c & 3;
                int kk = k0 + ck * 8;
                const unsigned short* gp = (kk < KS)
                    ? A  + (size_t)(m0 + row) * lda  + kk
                    : A2 + (size_t)(m0 + row) * lda2 + (kk - KS);
                gload_lds16(gp, As + (size_t)(i * 256 + wave * 64) * 8);
            }
        }
#pragma unroll
        for (int i = 0; i < (BCH + 255) / 256; ++i) {
            int c = i * 256 + tid;
            if (BCH % 256 == 0 || c < BCH) {
                int row = c >> 2, ck = c & 3;
                gload_lds16(Bt + (size_t)(n0 + row) * ldb + k0 + ck * 8,
                            Bs + (size_t)(i * 256 + wave * 64) * 8);
            }
        }
        __syncthreads();
        bh8 av[FM], bv[FN];
#pragma unroll
        for (int mi = 0; mi < FM; ++mi)
            av[mi] = *(const bh8*)((const char*)As + (((wr * FM + mi) * 16 + l16) * 64 + kh * 16));
#pragma unroll
        for (int ni = 0; ni < FN; ++ni)
            bv[ni] = *(const bh8*)((const char*)Bs + (((wc * FN + ni) * 16 + l16) * 64 + kh * 16));
#pragma unroll
        for (int mi = 0; mi < FM; ++mi)
#pragma unroll
            for (int ni = 0; ni < FN; ++ni)
                acc[mi][ni] = __builtin_amdgcn_mfma_f32_16x16x32_bf16(
                    av[mi], bv[ni], acc[mi][ni], 0, 0, 0);
        __syncthreads();
    }

#pragma unroll
    for (int mi = 0; mi < FM; ++mi) {
#pragma unroll
        for (int ni = 0; ni < FN; ++ni) {
            int col = n0 + (wc * FN + ni) * 16 + l16;
            float bcol = HAS_BIAS ? bias[col] : 0.f;
#pragma unroll
            for (int j = 0; j < 4; ++j) {
                int row = m0 + (wr * FM + mi) * 16 + kh * 4 + j;
                float v = acc[mi][ni][j] + bcol;
                if (ACT == 1) v = v * (1.f / (1.f + __expf(-v)));
                else if (ACT == 2) v = tanhf(v);
                if (ZPAD) {
                    int br = col >> 5, cc = col & 31;
                    unsigned short* zp = (unsigned short*)outp
                        + (size_t)br * NTH64 + (size_t)row * 64 + cc;
                    zp[0] = f2bf(v);
                    zp[32] = 0;
                } else if (OF32) {
                    ((float*)outp)[(size_t)row * ldo + col] = v;
                } else {
                    ((unsigned short*)outp)[(size_t)row * ldo + col] = f2bf(v);
                }
            }
        }
    }
}

// ====== bigproj (r7 core) + fused decay GEMM (blocks 0..127, run first) ====
// bigproj: 256x256 tile, BK=32, 8 waves, 4-ring, distance-2 counted vmcnt.
// decay:  tdmid = tanh([shifted|z0] @ Bcat1^T + bias0), BM=128xBN=64, 8 waves.
__global__ __launch_bounds__(512, 2) void bigproj8_kernel(
    const unsigned short* __restrict__ A,      // shifted [NROWS][2048]
    const unsigned short* __restrict__ zpad,   // [5][NROWS][64] (cols 32..63 = 0)
    const unsigned short* __restrict__ bt0, const unsigned short* __restrict__ bt1,
    const unsigned short* __restrict__ bt2, const unsigned short* __restrict__ bt3,
    const unsigned short* __restrict__ Bcat1,  // [64][KCAT]
    const float* __restrict__ bias4, const float* __restrict__ bias0,
    float* __restrict__ out, float* __restrict__ tdmid) {
    constexpr int BUFB = 32768;          // bytes per K-tile buffer (A 16K + B 16K)
    constexpr int NTK = KC8 / 32;        // 66 K-tiles; 0..63 in A, 64..65 in zpad
    __shared__ alignas(16) char lds[4 * BUFB];

    const int tid = threadIdx.x;
    const int wave = tid >> 6, lane = tid & 63;
    const int l16 = lane & 15, kh = lane >> 4;
    const int kh16 = kh * 16;

    if (blockIdx.x < 128) {
        // ---------------- fused decay GEMM ----------------
        unsigned short* As = (unsigned short*)lds;            // [128][32]
        unsigned short* Bs = (unsigned short*)(lds + 8192);   // [64][32]
        const int m0 = blockIdx.x * 128;
        f32x4 acc[4] = {};
        const int rowS = tid >> 2, ckS = tid & 3;
        for (int k0 = 0; k0 < KCAT; k0 += 32) {
            {   // stage A half (512 chunks, one per thread)
                int kk = k0 + ckS * 8;
                const unsigned short* gp = (kk < H)
                    ? A    + (size_t)(m0 + rowS) * H + kk
                    : zpad + (size_t)(m0 + rowS) * 64 + (kk - H);
                gload_lds16(gp, As + (size_t)(wave * 64) * 8);
            }
            if (tid < 256) {   // stage B (256 chunks)
                gload_lds16(Bcat1 + (size_t)rowS * KCAT + k0 + ckS * 8,
                            Bs + (size_t)(wave * 64) * 8);
            }
            __syncthreads();
            bh8 av = *(const bh8*)((const char*)As + ((wave * 16 + l16) * 64 + kh16));
#pragma unroll
            for (int ni = 0; ni < 4; ++ni) {
                bh8 bv = *(const bh8*)((const char*)Bs + ((ni * 16 + l16) * 64 + kh16));
                acc[ni] = __builtin_amdgcn_mfma_f32_16x16x32_bf16(av, bv, acc[ni], 0, 0, 0);
            }
            __syncthreads();
        }
#pragma unroll
        for (int ni = 0; ni < 4; ++ni) {
            int col = ni * 16 + l16;
            float bc = bias0[col];
#pragma unroll
            for (int j = 0; j < 4; ++j) {
                int row = m0 + wave * 16 + kh * 4 + j;
                tdmid[(size_t)row * 64 + col] = tanhf(acc[ni][j] + bc);
            }
        }
        return;
    }

    // ---------------- bigproj (r7 verbatim, bid2 over 2048) ----------------
    const int bid = blockIdx.x - 128;
    const int swz = (bid & 7) * 256 + (bid >> 3);    // bijective XCD swizzle
    const int branch = swz >> 9;                     // 0..3 = R,K,V,G
    const int tile = swz & 511;
    const int m0 = (tile >> 3) * 256, n0 = (tile & 7) * 256;

    const unsigned short* Bt = branch == 0 ? bt0 : branch == 1 ? bt1
                             : branch == 2 ? bt2 : bt3;
    const int f = (0x4213 >> (branch * 4)) & 15;     // fidx {3,1,2,4}
    const unsigned short* Az = zpad + (size_t)f * NTH64;

    const int wm = wave >> 2, wn = wave & 3;         // 2M x 4N waves
    const int swr = (l16 & 8) << 2;                  // read-side XOR (st_16x32)

    const int rS = tid >> 2;
    const int kbx = ((tid & 3) * 16) ^ ((rS & 8) << 2);
    const char* bA0 = (const char*)A  + (size_t)(m0 + rS) * 4096 + kbx;
    const char* bA1 = bA0 + (size_t)128 * 4096;
    const char* bz0 = (const char*)Az + (size_t)(m0 + rS) * 128 + kbx;
    const char* bz1 = bz0 + (size_t)128 * 128;
    const char* bB0 = (const char*)Bt + (size_t)(n0 + rS) * (KC8 * 2) + kbx;
    const char* bB1 = bB0 + (size_t)128 * (KC8 * 2);
    const int dA0 = wave * 1024, dA1 = 8192 + wave * 1024;

    auto stageA = [&](int kt, char* nb) {
        const char *p0, *p1;
        if (kt < 64) { size_t o = (size_t)kt * 64;        p0 = bA0 + o; p1 = bA1 + o; }
        else         { size_t o = (size_t)(kt - 64) * 64; p0 = bz0 + o; p1 = bz1 + o; }
        gload_lds16(p0, nb + dA0);
        gload_lds16(p1, nb + dA1);
    };
    auto stageB = [&](int kt, char* nb) {
        size_t o = (size_t)kt * 64;
        gload_lds16(bB0 + o, nb + 16384 + dA0);
        gload_lds16(bB1 + o, nb + 16384 + dA1);
    };

    f32x4 acc[8][4] = {};
    bh8 avlo[4], avhi[4], bvA[4], bvB[4];

    stageA(0, lds);        stageB(0, lds);
    stageA(1, lds + BUFB); stageB(1, lds + BUFB);
    asm volatile("s_waitcnt vmcnt(4)" ::: "memory");   // tile 0 complete
    __builtin_amdgcn_s_barrier();
    __builtin_amdgcn_sched_barrier(0);
#pragma unroll
    for (int i = 0; i < 4; ++i) {
        avlo[i] = *(const bh8*)(lds + (wm * 8 + i) * 1024 + l16 * 64 + (kh16 ^ swr));
        bvA[i]  = *(const bh8*)(lds + 16384 + (wn * 4 + i) * 1024 + l16 * 64 + (kh16 ^ swr));
    }

    auto tile_step = [&](int t, bh8 (&bvC)[4], bh8 (&bvN)[4]) {
        const char* Ab = lds + (t & 3) * BUFB;
        char* nb = lds + ((t + 2) & 3) * BUFB;
        const bool doSt = (t + 2) < NTK;

#pragma unroll
        for (int i = 0; i < 4; ++i)
            avhi[i] = *(const bh8*)(Ab + (wm * 8 + 4 + i) * 1024 + l16 * 64 + (kh16 ^ swr));
        if (doSt) stageA(t + 2, nb);
        __builtin_amdgcn_s_setprio(1);
#pragma unroll
        for (int mi = 0; mi < 4; ++mi)
#pragma unroll
            for (int ni = 0; ni < 4; ++ni)
                acc[mi][ni] = __builtin_amdgcn_mfma_f32_16x16x32_bf16(
                    avlo[mi], bvC[ni], acc[mi][ni], 0, 0, 0);
        __builtin_amdgcn_s_setprio(0);

        if (doSt) stageB(t + 2, nb);
        if (t + 1 < NTK) {
            if (doSt) asm volatile("s_waitcnt vmcnt(4)" ::: "memory");
            else      asm volatile("s_waitcnt vmcnt(0)" ::: "memory");
            __builtin_amdgcn_s_barrier();
            __builtin_amdgcn_sched_barrier(0);
            const char* Ab1 = lds + ((t + 1) & 3) * BUFB;
#pragma unroll
            for (int i = 0; i < 4; ++i) {
                avlo[i] = *(const bh8*)(Ab1 + (wm * 8 + i) * 1024 + l16 * 64 + (kh16 ^ swr));
                bvN[i]  = *(const bh8*)(Ab1 + 16384 + (wn * 4 + i) * 1024 + l16 * 64 + (kh16 ^ swr));
            }
        }
        __builtin_amdgcn_s_setprio(1);
#pragma unroll
        for (int mi = 0; mi < 4; ++mi)
#pragma unroll
            for (int ni = 0; ni < 4; ++ni)
                acc[4 + mi][ni] = __builtin_amdgcn_mfma_f32_16x16x32_bf16(
                    avhi[mi], bvC[ni], acc[4 + mi][ni], 0, 0, 0);
        __builtin_amdgcn_s_setprio(0);
    };

    for (int t = 0; t < NTK; t += 2) {
        tile_step(t,     bvA, bvB);
        tile_step(t + 1, bvB, bvA);
    }

    float* outp = out + (size_t)branch * NTH;
    const float* bias = bias4 + branch * H;
#pragma unroll
    for (int a = 0; a < 8; ++a) {
#pragma unroll
        for (int b = 0; b < 4; ++b) {
            int col = n0 + wn * 64 + b * 16 + l16;
            float bc = bias[col];
#pragma unroll
            for (int j = 0; j < 4; ++j) {
                int row = m0 + wm * 128 + a * 16 + kh * 4 + j;
                float v = acc[a][b][j] + bc;
                if (branch == 3) v = v * (1.f / (1.f + __expf(-v)));   // silu
                outp[(size_t)row * H + col] = v;
            }
        }
    }
}

// ------- td stage 2 (fp32 VALU): out = tdecay + tdmid(N x 64) @ W2d(64 x H) ----
__global__ __launch_bounds__(256) void td2_kernel(
    const float* __restrict__ tdmid, const float* __restrict__ W2d,
    const float* __restrict__ tdecay, float* __restrict__ outp) {
    int col = blockIdx.x * 256 + threadIdx.x;
    int row0 = blockIdx.y * 8;
    float a[8] = {0, 0, 0, 0, 0, 0, 0, 0};
    for (int r = 0; r < 64; ++r) {
        float w = W2d[(size_t)r * H + col];
#pragma unroll
        for (int j = 0; j < 8; ++j)
            a[j] += tdmid[(size_t)(row0 + j) * 64 + r] * w;
    }
    float b = tdecay[col];
#pragma unroll
    for (int j = 0; j < 8; ++j)
        outp[(size_t)(row0 + j) * H + col] = a[j] + b;
}

extern "C" void kernel_launch(void* const* d_in, const int* in_sizes, int n_in,
                              void* d_out, int out_size, void* d_ws, size_t ws_size,
                              hipStream_t stream) {
    const float* hidden = (const float*)d_in[0];
    const float* attn_x = (const float*)d_in[1];
    const float* tmx    = (const float*)d_in[4];
    const float* tmaa_w = (const float*)d_in[5];
    const float* tmaa_k = (const float*)d_in[6];
    const float* tmaa_v = (const float*)d_in[7];
    const float* tmaa_r = (const float*)d_in[8];
    const float* tmaa_g = (const float*)d_in[9];
    const float* W1     = (const float*)d_in[10];   // (H,160)
    const float* W2     = (const float*)d_in[11];   // (5,32,H)
    const float* tdecay = (const float*)d_in[12];   // (1,1,H)
    const float* W1d    = (const float*)d_in[13];   // (H,64)
    const float* W2d    = (const float*)d_in[14];   // (64,H)
    const float* Wr     = (const float*)d_in[16];
    const float* Wk     = (const float*)d_in[17];
    const float* Wv     = (const float*)d_in[18];
    const float* Wg     = (const float*)d_in[19];

    float* out = (float*)d_out;     // reference outputs are float32

    char* ws = (char*)d_ws;
    size_t off = 0;
    auto alloc = [&](size_t bytes) {
        char* p = ws + off;
        off = (off + bytes + 255) & ~(size_t)255;
        return p;
    };
    unsigned short* shifted = (unsigned short*)alloc(NTH * 2);
    unsigned short* xin     = (unsigned short*)alloc(NTH * 2);
    unsigned short* zpad    = (unsigned short*)alloc(5 * NTH64 * 2);
    unsigned short* W1t     = (unsigned short*)alloc((size_t)160 * H * 2);
    unsigned short* BcatR   = (unsigned short*)alloc((size_t)H * KC8 * 2);
    unsigned short* BcatK   = (unsigned short*)alloc((size_t)H * KC8 * 2);
    unsigned short* BcatV   = (unsigned short*)alloc((size_t)H * KC8 * 2);
    unsigned short* BcatG   = (unsigned short*)alloc((size_t)H * KC8 * 2);
    unsigned short* Bcat1   = (unsigned short*)alloc((size_t)64 * KCAT * 2);
    float* tdmid            = (float*)alloc((size_t)NROWS * 64 * 4);
    float* part             = (float*)alloc((size_t)5 * 8 * 33 * 2048 * 4);
    float* bias4            = (float*)alloc(4 * H * 4);
    float* bias0            = (float*)alloc(64 * 4);

    // 1. shifted / xin (+ fused attn_x_new copy)
    prep_kernel<<<(unsigned)(NTH / (4 * 256)), 256, 0, stream>>>(
        hidden, attn_x, tmx, shifted, xin, out + 5 * NTH);

    // 2. fused weights: transposes + K-split low-rank fusion (+ bias rows)
    transpose4_kernel<<<dim3(64, 64, 4), 256, 0, stream>>>(
        Wr, Wk, Wv, Wg, BcatR, BcatK, BcatV, BcatG);
    transpose_kernel<<<dim3(5, 64), 256, 0, stream>>>(W1, W1t, H, 160, H);
    transpose_kernel<<<dim3(2, 64), 256, 0, stream>>>(W1d, Bcat1, H, 64, KCAT);
    w2wp_kernel<<<dim3(8, 8, 5), 256, 0, stream>>>(
        W2, Wr, Wk, Wv, Wg, W1d,
        tmaa_r, tmaa_k, tmaa_v, tmaa_g, tmaa_w, part);
    w2wr_kernel<<<1065, 256, 0, stream>>>(
        part, BcatR, BcatK, BcatV, BcatG, Bcat1, bias4, bias0);

    // 3. z = tanh(xin @ W1) -> zpad [5][NROWS][64], cols 32..63 zeroed
    gemm_kernel<4, 1, 1, 10, 0, 2, 0, 1><<<256, 256, 0, stream>>>(
        xin, H, xin, H, H, W1t, H, H, zpad, 0, 1, nullptr);

    // 4. big projections (R,K,V,G) + fused decay GEMM (blocks 0..127)
    bigproj8_kernel<<<2176, 512, 0, stream>>>(
        shifted, zpad, BcatR, BcatK, BcatV, BcatG, Bcat1,
        bias4, bias0, out, tdmid);

    // 5. td = time_decay + tdmid @ W2d   (fp32 VALU, register-blocked)
    td2_kernel<<<dim3(8, NROWS / 8), 256, 0, stream>>>(
        tdmid, W2d, tdecay, out + 4 * NTH);
}